// Round 6
// baseline (57.685 us; speedup 1.0000x reference)
//
#include <hip/hip_runtime.h>
#include <cstdint>

#define B 32
#define T 40
#define V 64
#define H 768
#define M 64
#define POS_D 7
#define NCODE 64
#define NBINS 32
#define NBLK (B * NBINS)    // 1024 persistent blocks, 4/CU
#define NSTEP (B * T)       // 1280 step items (dynamic queue)
#define SEG 32              // per-wave member-list segment

// ---------------------------------------------------------------------------
// K1 (persistent): block j first computes bin item j (empty bins fall through
// immediately), then drains a dynamic queue of whole-(b,t) step-mean items.
// Queue assignment is nondeterministic but every item writes an exclusive
// region with fixed summation order -> bitwise-deterministic output.
// ---------------------------------------------------------------------------
__global__ __launch_bounds__(192, 3) void k1_kernel(
    const float* __restrict__ emb, const int* __restrict__ lens,
    const int* __restrict__ cand, const int* __restrict__ tvp,
    const int* __restrict__ gvp,
    float* __restrict__ step_mean,   // [B*T][H]
    float* __restrict__ Sdiv,        // [B*NBINS][H], pre-divided by cnt
    unsigned int* __restrict__ ctr)  // zeroed via hipMemsetAsync each launch
{
    const int tid = threadIdx.x;
    const int w = tid >> 6, lane = tid & 63;

    // ---------------- bin item (blockIdx.x = b*NBINS + bin) ----------------
    {
        const int bb = blockIdx.x;
        const int b = bb >> 5, bin = bb & 31;

        __shared__ int tvp_s[T], gvp_s[M], lens_s[T];
        __shared__ int code_s, cnt_s;
        __shared__ int list_s[3 * SEG];
        __shared__ int wcnt[3];

        if (tid < T) { tvp_s[tid] = tvp[b * T + tid]; lens_s[tid] = lens[b * T + tid]; }
        if (tid < M) gvp_s[tid] = gvp[b * M + tid];
        if (tid == 0) { code_s = -1; cnt_s = 0; }
        if (tid < 3) wcnt[tid] = 0;
        __syncthreads();

        // wave 0: which code does this bin own? (prefix rank of needed codes)
        if (tid < 64) {
            const int c = tid;
            bool mention = false;
            #pragma unroll 8
            for (int mm = 0; mm < M; ++mm) mention |= (gvp_s[mm] == c);
            bool vis = false;
            #pragma unroll 8
            for (int t = 0; t < T; ++t) vis |= (tvp_s[t] == c);
            const bool needed = mention && !vis;
            const unsigned long long mask = __ballot(needed);
            const int pre = __popcll(mask & ((1ull << c) - 1ull));
            if (needed && pre == bin) code_s = c;
        }
        __syncthreads();

        const int code = code_s;
        float ax = 0.f, ay = 0.f, az = 0.f, aw = 0.f;
        if (code >= 0) {
            // unmasked count of cand == code
            const int* cb = cand + b * T * V;
            int local = 0;
            for (int i = tid; i < T * V; i += 192) local += (cb[i] == code);
            #pragma unroll
            for (int off = 32; off; off >>= 1) local += __shfl_xor(local, off);
            if (lane == 0) atomicAdd(&cnt_s, local);

            // member list: wave w owns t = w, w+3, ...; fixed order
            int myn = 0;
            for (int t = w; t < T; t += 3) {
                const int cc = cb[t * V + lane];
                const bool ok = (lane < lens_s[t]) && (cc == code);
                const unsigned long long mk = __ballot(ok);
                if (ok) {
                    const int pos = myn + __popcll(mk & ((1ull << lane) - 1ull));
                    if (pos < SEG) list_s[w * SEG + pos] = t * V + lane;
                }
                myn += __popcll(mk);
            }
            if (lane == 0) wcnt[w] = min(myn, SEG);
            __syncthreads();

            const float* eb = emb + (size_t)b * T * V * H + tid * 4;
            for (int ww = 0; ww < 3; ++ww) {       // fixed segment order
                const int n = wcnt[ww];
                #pragma unroll 8
                for (int k = 0; k < n; ++k) {
                    const int tvx = list_s[ww * SEG + k];
                    const float4 x = *(const float4*)(eb + (size_t)tvx * H);
                    ax += x.x; ay += x.y; az += x.z; aw += x.w;
                }
            }
            const float inv = 1.0f / fmaxf((float)cnt_s, 1.0f);
            ax *= inv; ay *= inv; az *= inv; aw *= inv;
        }
        float4 o; o.x = ax; o.y = ay; o.z = az; o.w = aw;
        *(float4*)(Sdiv + (size_t)bb * H + tid * 4) = o;
    }

    // ---------------- step-mean items from dynamic queue ----------------
    __shared__ int item_s;
    for (;;) {
        __syncthreads();
        if (tid == 0) item_s = (int)atomicAdd(ctr, 1u);
        __syncthreads();
        const int it = item_s;
        if (it >= NSTEP) break;

        const int len = lens[it];
        const float* base = emb + (size_t)it * V * H + tid * 4;
        float ax = 0.f, ay = 0.f, az = 0.f, aw = 0.f;
        int v = 0;
        for (; v + 16 <= len; v += 16) {
            #pragma unroll
            for (int u = 0; u < 16; ++u) {
                const float4 x = *(const float4*)(base + (size_t)(v + u) * H);
                ax += x.x; ay += x.y; az += x.z; aw += x.w;
            }
        }
        #pragma unroll 4
        for (; v < len; ++v) {
            const float4 x = *(const float4*)(base + (size_t)v * H);
            ax += x.x; ay += x.y; az += x.z; aw += x.w;
        }
        const float inv = 1.0f / (float)len;
        float4 o; o.x = ax * inv; o.y = ay * inv; o.z = az * inv; o.w = aw * inv;
        *(float4*)(step_mean + (size_t)it * H + tid * 4) = o;
    }
}

// ---------------------------------------------------------------------------
// K2: one block per (b,m): agg gather + step_table + LN(pos @ W + b)
// ---------------------------------------------------------------------------
__global__ __launch_bounds__(192) void k2_kernel(
    const int* __restrict__ gvp, const int* __restrict__ tvp,
    const int* __restrict__ step_ids, const float* __restrict__ pos_fts,
    const float* __restrict__ step_mean, const float* __restrict__ Sdiv,
    const float* __restrict__ W_pos, const float* __restrict__ b_pos,
    const float* __restrict__ gamma, const float* __restrict__ beta,
    const float* __restrict__ step_tab, float* __restrict__ out)
{
    const int bm = blockIdx.x;
    const int b = bm >> 6;   // M == 64
    const int m = bm & 63;
    const int tid = threadIdx.x;
    const int hl = tid * 4;

    __shared__ int tvp_s[T], gvp_s[M];
    __shared__ unsigned long long needmask;
    if (tid < T) tvp_s[tid] = tvp[b * T + tid];
    if (tid < M) gvp_s[tid] = gvp[b * M + tid];
    __syncthreads();
    if (tid < 64) {
        const int c = tid;
        bool mention = false;
        #pragma unroll 8
        for (int mm = 0; mm < M; ++mm) mention |= (gvp_s[mm] == c);
        bool vis = false;
        #pragma unroll 8
        for (int t = 0; t < T; ++t) vis |= (tvp_s[t] == c);
        const unsigned long long mask = __ballot(mention && !vis);
        if (tid == 0) needmask = mask;
    }
    __syncthreads();

    const int g = gvp_s[m];
    float ax = 0.f, ay = 0.f, az = 0.f, aw = 0.f;
    if (m != 0 && g >= 0 && g < NCODE) {
        int lt = -1;
        #pragma unroll 8
        for (int t = 0; t < T; ++t) if (tvp_s[t] == g) lt = t;
        if (lt >= 0) {
            const float4 sm = *(const float4*)(
                step_mean + ((size_t)b * T + lt) * H + hl);
            ax = sm.x; ay = sm.y; az = sm.z; aw = sm.w;
        } else if ((needmask >> g) & 1ull) {
            const int bin = __popcll(needmask & ((1ull << g) - 1ull));
            if (bin < NBINS) {
                const float4 s = *(const float4*)(
                    Sdiv + ((size_t)b * NBINS + bin) * H + hl);
                ax = s.x; ay = s.y; az = s.z; aw = s.w;
            }
        }
    }

    float f[POS_D];
    #pragma unroll
    for (int d = 0; d < POS_D; ++d) f[d] = pos_fts[bm * POS_D + d];
    const float4 bp = *(const float4*)(b_pos + hl);
    float px = bp.x, py = bp.y, pz = bp.z, pw = bp.w;
    #pragma unroll
    for (int d = 0; d < POS_D; ++d) {
        const float4 wv4 = *(const float4*)(W_pos + d * H + hl);
        px += f[d] * wv4.x; py += f[d] * wv4.y; pz += f[d] * wv4.z; pw += f[d] * wv4.w;
    }

    float s1 = px + py + pz + pw;
    float s2 = px * px + py * py + pz * pz + pw * pw;
    #pragma unroll
    for (int off = 32; off > 0; off >>= 1) {
        s1 += __shfl_xor(s1, off);
        s2 += __shfl_xor(s2, off);
    }
    __shared__ float w1[3], w2[3];
    const int wv = tid >> 6;
    if ((tid & 63) == 0) { w1[wv] = s1; w2[wv] = s2; }
    __syncthreads();
    s1 = w1[0] + w1[1] + w1[2];
    s2 = w2[0] + w2[1] + w2[2];
    const float mu = s1 * (1.0f / H);
    const float var = fmaxf(s2 * (1.0f / H) - mu * mu, 0.f);
    const float rs = rsqrtf(var + 1e-12f);

    const float4 gm = *(const float4*)(gamma + hl);
    const float4 bt = *(const float4*)(beta + hl);
    const int sid = step_ids[bm];
    const float4 st = *(const float4*)(step_tab + (size_t)sid * H + hl);

    float4 o;
    o.x = ax + st.x + (px - mu) * rs * gm.x + bt.x;
    o.y = ay + st.y + (py - mu) * rs * gm.y + bt.y;
    o.z = az + st.z + (pz - mu) * rs * gm.z + bt.z;
    o.w = aw + st.w + (pw - mu) * rs * gm.w + bt.w;
    *(float4*)(out + (size_t)bm * H + hl) = o;
}

// ---------------------------------------------------------------------------
extern "C" void kernel_launch(void* const* d_in, const int* in_sizes, int n_in,
                              void* d_out, int out_size, void* d_ws, size_t ws_size,
                              hipStream_t stream)
{
    const float* emb      = (const float*)d_in[2];
    const int*   vp_lens  = (const int*)d_in[3];
    const int*   tvp      = (const int*)d_in[4];
    const int*   cand     = (const int*)d_in[5];
    const int*   gvp      = (const int*)d_in[6];
    const int*   step_ids = (const int*)d_in[7];
    const float* pos_fts  = (const float*)d_in[8];
    const float* W_pos    = (const float*)d_in[10];
    const float* b_pos    = (const float*)d_in[11];
    const float* gamma    = (const float*)d_in[12];
    const float* beta     = (const float*)d_in[13];
    const float* step_tab = (const float*)d_in[14];
    float* out = (float*)d_out;

    char* ws = (char*)d_ws;
    size_t off = 0;
    float* step_mean = (float*)(ws + off); off += (size_t)NSTEP * H * sizeof(float);    // 3.9 MB
    float* Sdiv      = (float*)(ws + off); off += (size_t)B * NBINS * H * sizeof(float); // 3.1 MB
    unsigned int* ctr = (unsigned int*)(ws + off); off += 256;

    hipMemsetAsync(ctr, 0, sizeof(unsigned int), stream);
    k1_kernel<<<NBLK, 192, 0, stream>>>(emb, vp_lens, cand, tvp, gvp,
                                        step_mean, Sdiv, ctr);
    k2_kernel<<<B * M, 192, 0, stream>>>(gvp, tvp, step_ids, pos_fts,
                                         step_mean, Sdiv, W_pos, b_pos,
                                         gamma, beta, step_tab, out);
}

// Round 8
// 43.197 us; speedup vs baseline: 1.3354x; 1.3354x over previous
//
#include <hip/hip_runtime.h>
#include <cstdint>

#define B 32
#define T 40
#define V 64
#define H 768
#define M 64
#define POS_D 7
#define NCODE 64
#define SEG 48                   // per-wave member-list segment
#define NBIN_BLKS (B * NCODE)    // 2048 (empties exit immediately)
#define NSTEP (B * T)            // 1280
#define NTAIL B                  // 32 catch-all blocks (m==0 / invalid code)

// ---------------------------------------------------------------------------
// Epilogue for one output (b,m): out = agg + step_table[sid] + LN(pos@W + b).
// Must be called block-uniformly. agg held in registers (4 floats / thread).
// ---------------------------------------------------------------------------
__device__ __forceinline__ void epilogue(
    int b, int m, float ax, float ay, float az, float aw,
    const float* __restrict__ pos_fts, const float* __restrict__ W_pos,
    const float* __restrict__ b_pos, const float* __restrict__ gamma,
    const float* __restrict__ beta, const int* __restrict__ step_ids,
    const float* __restrict__ step_tab, float* __restrict__ out,
    float* w1, float* w2)
{
    const int tid = threadIdx.x;
    const int hl = tid * 4;
    const int bm = b * M + m;

    float f[POS_D];
    #pragma unroll
    for (int d = 0; d < POS_D; ++d) f[d] = pos_fts[bm * POS_D + d];
    const float4 bp = *(const float4*)(b_pos + hl);
    float px = bp.x, py = bp.y, pz = bp.z, pw = bp.w;
    #pragma unroll
    for (int d = 0; d < POS_D; ++d) {
        const float4 wv4 = *(const float4*)(W_pos + d * H + hl);
        px += f[d] * wv4.x; py += f[d] * wv4.y;
        pz += f[d] * wv4.z; pw += f[d] * wv4.w;
    }

    float s1 = px + py + pz + pw;
    float s2 = px * px + py * py + pz * pz + pw * pw;
    #pragma unroll
    for (int off = 32; off > 0; off >>= 1) {
        s1 += __shfl_xor(s1, off);
        s2 += __shfl_xor(s2, off);
    }
    __syncthreads();                       // guard w1/w2 reuse across calls
    const int wv = tid >> 6;
    if ((tid & 63) == 0) { w1[wv] = s1; w2[wv] = s2; }
    __syncthreads();
    s1 = w1[0] + w1[1] + w1[2];
    s2 = w2[0] + w2[1] + w2[2];
    const float mu = s1 * (1.0f / H);
    const float var = fmaxf(s2 * (1.0f / H) - mu * mu, 0.f);
    const float rs = rsqrtf(var + 1e-12f);

    const float4 gm = *(const float4*)(gamma + hl);
    const float4 bt4 = *(const float4*)(beta + hl);
    const int sid = step_ids[bm];
    const float4 st = *(const float4*)(step_tab + (size_t)sid * H + hl);

    float4 o;
    o.x = ax + st.x + (px - mu) * rs * gm.x + bt4.x;
    o.y = ay + st.y + (py - mu) * rs * gm.y + bt4.y;
    o.z = az + st.z + (pz - mu) * rs * gm.z + bt4.z;
    o.w = aw + st.w + (pw - mu) * rs * gm.w + bt4.w;
    *(float4*)(out + (size_t)bm * H + hl) = o;
}

// ---------------------------------------------------------------------------
// Single kernel, three block classes, disjoint outputs, zero workspace:
//  [0, NBIN_BLKS):    unvisited-code bins — gather + mean + epilogue(s)
//  [.., +NSTEP):      step means — stream + mean + epilogue(s) for all m
//                     whose code matches (only the last-t owner proceeds)
//  [.., +NTAIL):      catch-all — m==0 or invalid code -> agg = 0
// ---------------------------------------------------------------------------
__global__ __launch_bounds__(192) void fused_kernel(
    const float* __restrict__ emb, const int* __restrict__ lens,
    const int* __restrict__ cand, const int* __restrict__ tvp,
    const int* __restrict__ gvp, const int* __restrict__ step_ids,
    const float* __restrict__ pos_fts, const float* __restrict__ W_pos,
    const float* __restrict__ b_pos, const float* __restrict__ gamma,
    const float* __restrict__ beta, const float* __restrict__ step_tab,
    float* __restrict__ out)
{
    const int tid = threadIdx.x;
    const int blk = blockIdx.x;
    const int w = tid >> 6, lane = tid & 63;

    __shared__ int tvp_s[T], gvp_s[M], lens_s[T];
    __shared__ int code_s, cnt_s;
    __shared__ int list_s[3 * SEG];
    __shared__ int wcnt[3];
    __shared__ float w1[3], w2[3];

    if (blk < NBIN_BLKS) {
        // ================= bin path: (b, rank) =================
        const int b = blk >> 6, bin = blk & 63;

        if (tid < T) { tvp_s[tid] = tvp[b * T + tid]; lens_s[tid] = lens[b * T + tid]; }
        if (tid < M) gvp_s[tid] = gvp[b * M + tid];
        if (tid == 0) { code_s = -1; cnt_s = 0; }
        if (tid < 3) wcnt[tid] = 0;
        __syncthreads();

        // wave 0: rank the needed (mentioned && unvisited) codes
        if (tid < 64) {
            const int c = tid;
            bool mention = false;
            #pragma unroll 8
            for (int mm = 0; mm < M; ++mm) mention |= (gvp_s[mm] == c);
            bool vis = false;
            #pragma unroll 8
            for (int t = 0; t < T; ++t) vis |= (tvp_s[t] == c);
            const bool needed = mention && !vis;
            const unsigned long long mask = __ballot(needed);
            const int pre = __popcll(mask & ((1ull << c) - 1ull));
            if (needed && pre == bin) code_s = c;
        }
        __syncthreads();

        const int code = code_s;           // block-uniform
        if (code < 0) return;              // empty bin

        // unmasked count of cand == code
        const int* cb = cand + b * T * V;
        int local = 0;
        for (int i = tid; i < T * V; i += 192) local += (cb[i] == code);
        #pragma unroll
        for (int off = 32; off; off >>= 1) local += __shfl_xor(local, off);
        if (lane == 0) atomicAdd(&cnt_s, local);

        // member list (len-masked), wave w owns t = w, w+3, ...; fixed order
        int myn = 0;
        for (int t = w; t < T; t += 3) {
            const int cc = cb[t * V + lane];
            const bool ok = (lane < lens_s[t]) && (cc == code);
            const unsigned long long mk = __ballot(ok);
            if (ok) {
                const int pos = myn + __popcll(mk & ((1ull << lane) - 1ull));
                if (pos < SEG) list_s[w * SEG + pos] = t * V + lane;
            }
            myn += __popcll(mk);
        }
        if (lane == 0) wcnt[w] = min(myn, SEG);
        __syncthreads();

        float ax = 0.f, ay = 0.f, az = 0.f, aw = 0.f;
        const float* eb = emb + (size_t)b * T * V * H + tid * 4;
        for (int ww = 0; ww < 3; ++ww) {   // fixed segment order
            const int n = wcnt[ww];
            #pragma unroll 8
            for (int k = 0; k < n; ++k) {
                const int tvx = list_s[ww * SEG + k];
                const float4 x = *(const float4*)(eb + (size_t)tvx * H);
                ax += x.x; ay += x.y; az += x.z; aw += x.w;
            }
        }
        const float inv = 1.0f / fmaxf((float)cnt_s, 1.0f);
        ax *= inv; ay *= inv; az *= inv; aw *= inv;

        for (int m = 1; m < M; ++m)
            if (gvp_s[m] == code)
                epilogue(b, m, ax, ay, az, aw, pos_fts, W_pos, b_pos,
                         gamma, beta, step_ids, step_tab, out, w1, w2);
        return;
    }

    if (blk < NBIN_BLKS + NSTEP) {
        // ================= step path: (b, t) =================
        const int bt = blk - NBIN_BLKS;
        const int b = bt / T, t = bt - b * T;

        if (tid < T) tvp_s[tid] = tvp[b * T + tid];
        if (tid < M) gvp_s[tid] = gvp[b * M + tid];
        __syncthreads();

        const int c = tvp_s[t];
        int lt = -1;
        #pragma unroll 8
        for (int tt = 0; tt < T; ++tt) if (tvp_s[tt] == c) lt = tt;
        if (lt != t) return;               // another block owns this code

        bool any = false;
        #pragma unroll 8
        for (int m = 1; m < M; ++m) any |= (gvp_s[m] == c);
        if (!any) return;                  // no consumer

        const int len = lens[bt];
        const float* base = emb + (size_t)bt * V * H + tid * 4;
        float ax = 0.f, ay = 0.f, az = 0.f, aw = 0.f;
        int v = 0;
        for (; v + 16 <= len; v += 16) {
            #pragma unroll
            for (int u = 0; u < 16; ++u) {
                const float4 x = *(const float4*)(base + (size_t)(v + u) * H);
                ax += x.x; ay += x.y; az += x.z; aw += x.w;
            }
        }
        #pragma unroll 4
        for (; v < len; ++v) {
            const float4 x = *(const float4*)(base + (size_t)v * H);
            ax += x.x; ay += x.y; az += x.z; aw += x.w;
        }
        const float inv = 1.0f / (float)len;
        ax *= inv; ay *= inv; az *= inv; aw *= inv;

        for (int m = 1; m < M; ++m)
            if (gvp_s[m] == c)
                epilogue(b, m, ax, ay, az, aw, pos_fts, W_pos, b_pos,
                         gamma, beta, step_ids, step_tab, out, w1, w2);
        return;
    }

    // ================= catch-all path: one block per batch =================
    {
        const int b = blk - (NBIN_BLKS + NSTEP);
        if (tid < M) gvp_s[tid] = gvp[b * M + tid];
        __syncthreads();
        for (int m = 0; m < M; ++m) {
            const int g = gvp_s[m];
            const bool handled = (m != 0) && (g >= 0) && (g < NCODE);
            if (!handled)
                epilogue(b, m, 0.f, 0.f, 0.f, 0.f, pos_fts, W_pos, b_pos,
                         gamma, beta, step_ids, step_tab, out, w1, w2);
        }
    }
}

// ---------------------------------------------------------------------------
extern "C" void kernel_launch(void* const* d_in, const int* in_sizes, int n_in,
                              void* d_out, int out_size, void* d_ws, size_t ws_size,
                              hipStream_t stream)
{
    const float* emb      = (const float*)d_in[2];
    const int*   vp_lens  = (const int*)d_in[3];
    const int*   tvp      = (const int*)d_in[4];
    const int*   cand     = (const int*)d_in[5];
    const int*   gvp      = (const int*)d_in[6];
    const int*   step_ids = (const int*)d_in[7];
    const float* pos_fts  = (const float*)d_in[8];
    const float* W_pos    = (const float*)d_in[10];
    const float* b_pos    = (const float*)d_in[11];
    const float* gamma    = (const float*)d_in[12];
    const float* beta     = (const float*)d_in[13];
    const float* step_tab = (const float*)d_in[14];
    float* out = (float*)d_out;

    fused_kernel<<<NBIN_BLKS + NSTEP + NTAIL, 192, 0, stream>>>(
        emb, vp_lens, cand, tvp, gvp, step_ids, pos_fts,
        W_pos, b_pos, gamma, beta, step_tab, out);
}